// Round 15
// baseline (19.195 us; speedup 1.0000x reference)
//
#include <hip/hip_runtime.h>

// Fused NeRF: PE (4 freq) + MLP 27->32->1 via 32x32x16 bf16 MFMA (K=28->2x16).
// R14: TILES 4->8 (512 WGs; prologue amortized over 2x points; R6 showed
// 4 vs 8 waves/SIMD costs ~1%) + TABN 4096->2048 (half the table-build trans).

#define NPTS  2097152
#define BLOCK 512
#define TILES 8
#define NBLK  (NPTS / (64 * (BLOCK / 64) * TILES))   // 512
#define TABN  2048

typedef __bf16 bf16x8 __attribute__((ext_vector_type(8)));
typedef __bf16 bf16x2 __attribute__((ext_vector_type(2)));
typedef float  f32x8  __attribute__((ext_vector_type(8)));
typedef float  f32x16 __attribute__((ext_vector_type(16)));
typedef float  f32x2  __attribute__((ext_vector_type(2)));
typedef unsigned int u32;
typedef u32 u32x4 __attribute__((ext_vector_type(4)));

__global__ __launch_bounds__(BLOCK, 4) void nerf_32x32b(
    const float* __restrict__ x,
    const float* __restrict__ W1,
    const float* __restrict__ b1,
    const float* __restrict__ W2,
    const float* __restrict__ b2,
    float* __restrict__ out)
{
    __shared__ u32 stab[TABN];                 // {bf16 sin | bf16 cos<<16}
    __shared__ __align__(16) float ws[928];    // W1 (864) | b1 (32) | W2 (32)

    const int tid  = threadIdx.x;
    const int wave = tid >> 6;
    const int lane = tid & 63;
    const int h    = lane >> 5;   // k-half: bands {h, 2+h}
    const int col  = lane & 31;   // point-in-group / hidden j (A operand)

    // ---- cooperative weight stage (coalesced float4) ----
    if (tid < 232) {
        float4 v;
        if (tid < 216)      v = ((const float4*)W1)[tid];
        else if (tid < 224) v = ((const float4*)b1)[tid - 216];
        else                v = ((const float4*)W2)[tid - 224];
        ((float4*)ws)[tid] = v;
    }
    // ---- packed sincos table (4 iters/thread) ----
    #pragma unroll
    for (int i = 0; i < TABN / BLOCK; ++i) {
        const int idx = tid + i * BLOCK;
        const float a = (float)idx * (1.0f / TABN);
        f32x2 sc;
        sc[0] = __builtin_amdgcn_sinf(a);
        sc[1] = __builtin_amdgcn_cosf(a);
        stab[idx] = __builtin_bit_cast(u32, __builtin_convertvector(sc, bf16x2));
    }

    // per-lane band scales -> BYTE offset into stab
    const float C4 = 0.15915494309189535f * (float)TABN * 4.0f;
    const float FgA = (h ? 10.0793684f : 1.0f)         * C4;
    const float FgB = (h ? 1024.0f     : 101.5936673f) * C4;
    const float bias2 = b2[0];
    const f32x16 Z = {};

    __syncthreads();

    // ---- layer-1 A fragments from LDS (permuted k-order), j = col ----
    bf16x8 af1, af2;
    {
        f32x8 t1, t2;
        #pragma unroll
        for (int m = 0; m < 3; ++m) {
            t1[2 * m]     = ws[(3  + 6 * h + m) * 32 + col];
            t1[2 * m + 1] = ws[(6  + 6 * h + m) * 32 + col];
            t2[2 * m]     = ws[(15 + 6 * h + m) * 32 + col];
            t2[2 * m + 1] = ws[(18 + 6 * h + m) * 32 + col];
        }
        t1[6] = h ? ws[2 * 32 + col] : ws[0 * 32 + col];
        t1[7] = h ? ws[864 + col]    : ws[1 * 32 + col];   // bias | x1-row
        t2[6] = 0.0f; t2[7] = 0.0f;
        af1 = __builtin_convertvector(t1, bf16x8);
        af2 = __builtin_convertvector(t2, bf16x8);
    }
    // layer-2 weights for lane's 16 C/D rows (pairs for pk_fma)
    f32x2 w2p[8];
    #pragma unroll
    for (int m = 0; m < 8; ++m) {
        const int r0 = 896 + 8 * (m >> 1) + 4 * h + 2 * (m & 1);
        w2p[m][0] = ws[r0];
        w2p[m][1] = ws[r0 + 1];
    }

    const char* stabB = (const char*)stab;
    const int tbase = blockIdx.x * ((BLOCK / 64) * TILES) + wave * TILES;
    const float* xb = x + (size_t)tbase * 192 + col * 3;   // my col's base
    float* ob = out + (size_t)tbase * 64 + lane;

    #pragma unroll
    for (int t = 0; t < TILES; ++t) {
        float S[2];
        #pragma unroll
        for (int gr = 0; gr < 2; ++gr) {
            // my point for this group: 64t + 32gr + col (imm offsets)
            const float x0 = xb[t * 192 + gr * 96 + 0];
            const float x1 = xb[t * 192 + gr * 96 + 1];
            const float x2 = xb[t * 192 + gr * 96 + 2];

            // 6 packed {sin,cos} lookups: bands h (MFMA1) and 2+h (MFMA2)
            const u32 mA0 = (u32)(int)(x0 * FgA) & (4 * (TABN - 1));
            const u32 mA1 = (u32)(int)(x1 * FgA) & (4 * (TABN - 1));
            const u32 mA2 = (u32)(int)(x2 * FgA) & (4 * (TABN - 1));
            const u32 mB0 = (u32)(int)(x0 * FgB) & (4 * (TABN - 1));
            const u32 mB1 = (u32)(int)(x1 * FgB) & (4 * (TABN - 1));
            const u32 mB2 = (u32)(int)(x2 * FgB) & (4 * (TABN - 1));

            u32x4 u1, u2;
            u1[0] = *(const u32*)(stabB + mA0);
            u1[1] = *(const u32*)(stabB + mA1);
            u1[2] = *(const u32*)(stabB + mA2);
            f32x2 ex;
            ex[0] = h ? x2 : x0;
            ex[1] = h ? 1.0f : x1;     // bias multiplier lives in h=1
            u1[3] = __builtin_bit_cast(u32, __builtin_convertvector(ex, bf16x2));
            u2[0] = *(const u32*)(stabB + mB0);
            u2[1] = *(const u32*)(stabB + mB1);
            u2[2] = *(const u32*)(stabB + mB2);
            u2[3] = 0u;
            const bf16x8 B1 = __builtin_bit_cast(bf16x8, u1);
            const bf16x8 B2 = __builtin_bit_cast(bf16x8, u2);

            // layer 1: 2 chained 32x32x16 MFMAs -> 32 hidden x 32 points
            f32x16 acc = __builtin_amdgcn_mfma_f32_32x32x16_bf16(af1, B1, Z, 0, 0, 0);
            acc = __builtin_amdgcn_mfma_f32_32x32x16_bf16(af2, B2, acc, 0, 0, 0);

            // layer 2: relu + pk_fma over lane's 16 rows, fold halves
            f32x2 ps = {0.0f, 0.0f};
            #pragma unroll
            for (int m = 0; m < 8; ++m) {
                f32x2 v = {acc[2 * m], acc[2 * m + 1]};
                f32x2 zz = {0.f, 0.f};
                v = __builtin_elementwise_max(v, zz);
                ps = ps + v * w2p[m];
            }
            float s = ps[0] + ps[1];
            s += __shfl_xor(s, 32, 64);   // combine k-halves
            S[gr] = s;
        }
        // lane (h,col) stores point 32h+col of the tile
        const float v = h ? S[1] : S[0];
        ob[t * 64] = fmaxf(v + bias2, 0.0f);
    }
}

extern "C" void kernel_launch(void* const* d_in, const int* in_sizes, int n_in,
                              void* d_out, int out_size, void* d_ws, size_t ws_size,
                              hipStream_t stream) {
    const float* x  = (const float*)d_in[0];
    const float* W1 = (const float*)d_in[1];
    const float* b1 = (const float*)d_in[2];
    const float* W2 = (const float*)d_in[3];
    const float* b2 = (const float*)d_in[4];
    float* out = (float*)d_out;

    nerf_32x32b<<<NBLK, BLOCK, 0, stream>>>(x, W1, b1, W2, b2, out);
}

// Round 16
// 18.024 us; speedup vs baseline: 1.0650x; 1.0650x over previous
//
#include <hip/hip_runtime.h>

// Fused NeRF: PE (4 freq) + MLP 27->32->1 via 32x32x16 bf16 MFMA (K=28->2x16).
// R15: BLOCK=1024 (512 WGs, HALF the dispatch ramp, same 8192 waves = 8/SIMD)
// + TABN=1024 (table build = ONE sin+cos per thread, no loop; 8KB LDS).
// Inner loop identical to R13 (best known: 17.99 us).

#define NPTS  2097152
#define BLOCK 1024
#define TILES 4
#define NBLK  (NPTS / (64 * (BLOCK / 64) * TILES))   // 512
#define TABN  1024

typedef __bf16 bf16x8 __attribute__((ext_vector_type(8)));
typedef __bf16 bf16x2 __attribute__((ext_vector_type(2)));
typedef float  f32x8  __attribute__((ext_vector_type(8)));
typedef float  f32x16 __attribute__((ext_vector_type(16)));
typedef float  f32x2  __attribute__((ext_vector_type(2)));
typedef unsigned int u32;
typedef u32 u32x4 __attribute__((ext_vector_type(4)));

__global__ __launch_bounds__(BLOCK, 2) void nerf_32x32c(
    const float* __restrict__ x,
    const float* __restrict__ W1,
    const float* __restrict__ b1,
    const float* __restrict__ W2,
    const float* __restrict__ b2,
    float* __restrict__ out)
{
    __shared__ u32 stab[TABN];                 // {bf16 sin | bf16 cos<<16}
    __shared__ __align__(16) float ws[928];    // W1 (864) | b1 (32) | W2 (32)

    const int tid  = threadIdx.x;
    const int wave = tid >> 6;
    const int lane = tid & 63;
    const int h    = lane >> 5;   // k-half: bands {h, 2+h}
    const int col  = lane & 31;   // point-in-group / hidden j (A operand)

    // ---- cooperative weight stage (coalesced float4) ----
    if (tid < 232) {
        float4 v;
        if (tid < 216)      v = ((const float4*)W1)[tid];
        else if (tid < 224) v = ((const float4*)b1)[tid - 216];
        else                v = ((const float4*)W2)[tid - 224];
        ((float4*)ws)[tid] = v;
    }
    // ---- packed sincos table: exactly one entry per thread ----
    if (tid < TABN) {
        const float a = (float)tid * (1.0f / TABN);
        f32x2 sc;
        sc[0] = __builtin_amdgcn_sinf(a);
        sc[1] = __builtin_amdgcn_cosf(a);
        stab[tid] = __builtin_bit_cast(u32, __builtin_convertvector(sc, bf16x2));
    }

    // per-lane band scales -> BYTE offset into stab
    const float C4 = 0.15915494309189535f * (float)TABN * 4.0f;
    const float FgA = (h ? 10.0793684f : 1.0f)         * C4;
    const float FgB = (h ? 1024.0f     : 101.5936673f) * C4;
    const float bias2 = b2[0];
    const f32x16 Z = {};

    __syncthreads();

    // ---- layer-1 A fragments from LDS (permuted k-order), j = col ----
    bf16x8 af1, af2;
    {
        f32x8 t1, t2;
        #pragma unroll
        for (int m = 0; m < 3; ++m) {
            t1[2 * m]     = ws[(3  + 6 * h + m) * 32 + col];
            t1[2 * m + 1] = ws[(6  + 6 * h + m) * 32 + col];
            t2[2 * m]     = ws[(15 + 6 * h + m) * 32 + col];
            t2[2 * m + 1] = ws[(18 + 6 * h + m) * 32 + col];
        }
        t1[6] = h ? ws[2 * 32 + col] : ws[0 * 32 + col];
        t1[7] = h ? ws[864 + col]    : ws[1 * 32 + col];   // bias | x1-row
        t2[6] = 0.0f; t2[7] = 0.0f;
        af1 = __builtin_convertvector(t1, bf16x8);
        af2 = __builtin_convertvector(t2, bf16x8);
    }
    // layer-2 weights for lane's 16 C/D rows (pairs for pk_fma)
    f32x2 w2p[8];
    #pragma unroll
    for (int m = 0; m < 8; ++m) {
        const int r0 = 896 + 8 * (m >> 1) + 4 * h + 2 * (m & 1);
        w2p[m][0] = ws[r0];
        w2p[m][1] = ws[r0 + 1];
    }

    const char* stabB = (const char*)stab;
    const int tbase = blockIdx.x * ((BLOCK / 64) * TILES) + wave * TILES;
    const float* xb = x + (size_t)tbase * 192 + col * 3;   // my col's base
    float* ob = out + (size_t)tbase * 64 + lane;

    #pragma unroll
    for (int t = 0; t < TILES; ++t) {
        float S[2];
        #pragma unroll
        for (int gr = 0; gr < 2; ++gr) {
            // my point for this group: 64t + 32gr + col (imm offsets)
            const float x0 = xb[t * 192 + gr * 96 + 0];
            const float x1 = xb[t * 192 + gr * 96 + 1];
            const float x2 = xb[t * 192 + gr * 96 + 2];

            // 6 packed {sin,cos} lookups: bands h (MFMA1) and 2+h (MFMA2)
            const u32 mA0 = (u32)(int)(x0 * FgA) & (4 * (TABN - 1));
            const u32 mA1 = (u32)(int)(x1 * FgA) & (4 * (TABN - 1));
            const u32 mA2 = (u32)(int)(x2 * FgA) & (4 * (TABN - 1));
            const u32 mB0 = (u32)(int)(x0 * FgB) & (4 * (TABN - 1));
            const u32 mB1 = (u32)(int)(x1 * FgB) & (4 * (TABN - 1));
            const u32 mB2 = (u32)(int)(x2 * FgB) & (4 * (TABN - 1));

            u32x4 u1, u2;
            u1[0] = *(const u32*)(stabB + mA0);
            u1[1] = *(const u32*)(stabB + mA1);
            u1[2] = *(const u32*)(stabB + mA2);
            f32x2 ex;
            ex[0] = h ? x2 : x0;
            ex[1] = h ? 1.0f : x1;     // bias multiplier lives in h=1
            u1[3] = __builtin_bit_cast(u32, __builtin_convertvector(ex, bf16x2));
            u2[0] = *(const u32*)(stabB + mB0);
            u2[1] = *(const u32*)(stabB + mB1);
            u2[2] = *(const u32*)(stabB + mB2);
            u2[3] = 0u;
            const bf16x8 B1 = __builtin_bit_cast(bf16x8, u1);
            const bf16x8 B2 = __builtin_bit_cast(bf16x8, u2);

            // layer 1: 2 chained 32x32x16 MFMAs -> 32 hidden x 32 points
            f32x16 acc = __builtin_amdgcn_mfma_f32_32x32x16_bf16(af1, B1, Z, 0, 0, 0);
            acc = __builtin_amdgcn_mfma_f32_32x32x16_bf16(af2, B2, acc, 0, 0, 0);

            // layer 2: relu + pk_fma over lane's 16 rows, fold halves
            f32x2 ps = {0.0f, 0.0f};
            #pragma unroll
            for (int m = 0; m < 8; ++m) {
                f32x2 v = {acc[2 * m], acc[2 * m + 1]};
                f32x2 zz = {0.f, 0.f};
                v = __builtin_elementwise_max(v, zz);
                ps = ps + v * w2p[m];
            }
            float s = ps[0] + ps[1];
            s += __shfl_xor(s, 32, 64);   // combine k-halves
            S[gr] = s;
        }
        // lane (h,col) stores point 32h+col of the tile
        const float v = h ? S[1] : S[0];
        ob[t * 64] = fmaxf(v + bias2, 0.0f);
    }
}

extern "C" void kernel_launch(void* const* d_in, const int* in_sizes, int n_in,
                              void* d_out, int out_size, void* d_ws, size_t ws_size,
                              hipStream_t stream) {
    const float* x  = (const float*)d_in[0];
    const float* W1 = (const float*)d_in[1];
    const float* b1 = (const float*)d_in[2];
    const float* W2 = (const float*)d_in[3];
    const float* b2 = (const float*)d_in[4];
    float* out = (float*)d_out;

    nerf_32x32c<<<NBLK, BLOCK, 0, stream>>>(x, W1, b1, W2, b2, out);
}

// Round 17
// 17.910 us; speedup vs baseline: 1.0717x; 1.0064x over previous
//
#include <hip/hip_runtime.h>

// Fused NeRF: PE (4 freq) + MLP 27->32->1 via 32x32x16 bf16 MFMA (K=28->2x16).
// R16: ZERO LDS. R13's per-CU LDS pipe was ~7us serialized (random-bank table
// reads + fragment reads, 32 waves sharing one pipe). sincos -> v_fract+v_sin/
// v_cos (separate trans pipe, 12/32pts); weights gathered from global (L1-
// resident, 3.7KB); no __syncthreads. Inner structure otherwise identical R13.

#define NPTS  2097152
#define BLOCK 512
#define TILES 4
#define NBLK  (NPTS / (64 * (BLOCK / 64) * TILES))   // 1024

typedef __bf16 bf16x8 __attribute__((ext_vector_type(8)));
typedef __bf16 bf16x2 __attribute__((ext_vector_type(2)));
typedef float  f32x8  __attribute__((ext_vector_type(8)));
typedef float  f32x16 __attribute__((ext_vector_type(16)));
typedef float  f32x2  __attribute__((ext_vector_type(2)));
typedef unsigned int u32;
typedef u32 u32x4 __attribute__((ext_vector_type(4)));

__device__ __forceinline__ u32 pk_sc(float ang /*revolutions*/) {
    const float a = __builtin_amdgcn_fractf(ang);
    f32x2 sc;
    sc[0] = __builtin_amdgcn_sinf(a);
    sc[1] = __builtin_amdgcn_cosf(a);
    return __builtin_bit_cast(u32, __builtin_convertvector(sc, bf16x2));
}

__global__ __launch_bounds__(BLOCK, 4) void nerf_nolds(
    const float* __restrict__ x,
    const float* __restrict__ W1,
    const float* __restrict__ b1,
    const float* __restrict__ W2,
    const float* __restrict__ b2,
    float* __restrict__ out)
{
    const int tid  = threadIdx.x;
    const int wave = tid >> 6;
    const int lane = tid & 63;
    const int h    = lane >> 5;   // k-half: bands {h, 2+h}
    const int col  = lane & 31;   // point-in-group / hidden j (A operand)

    // per-lane band scales in revolutions
    const float INV2PI = 0.15915494309189535f;
    const float FgA = (h ? 10.0793684f : 1.0f)         * INV2PI;
    const float FgB = (h ? 1024.0f     : 101.5936673f) * INV2PI;
    const float bias2 = b2[0];
    const f32x16 Z = {};

    // ---- layer-1 A fragments gathered from GLOBAL (L1-resident weights) ----
    // k-order: MFMA1 i=2m sin_h(x_m) row 3+6h+m; i=2m+1 cos_h row 6+6h+m;
    //          i=6: h?x2:x0 (row 2|0); i=7: h?bias:x1 (b1|row 1).
    //          MFMA2 rows 15+6h+m / 18+6h+m; i=6,7 zero.
    bf16x8 af1, af2;
    {
        f32x8 t1, t2;
        #pragma unroll
        for (int m = 0; m < 3; ++m) {
            t1[2 * m]     = W1[(3  + 6 * h + m) * 32 + col];
            t1[2 * m + 1] = W1[(6  + 6 * h + m) * 32 + col];
            t2[2 * m]     = W1[(15 + 6 * h + m) * 32 + col];
            t2[2 * m + 1] = W1[(18 + 6 * h + m) * 32 + col];
        }
        t1[6] = h ? W1[2 * 32 + col] : W1[0 * 32 + col];
        t1[7] = h ? b1[col]          : W1[1 * 32 + col];   // bias | x1-row
        t2[6] = 0.0f; t2[7] = 0.0f;
        af1 = __builtin_convertvector(t1, bf16x8);
        af2 = __builtin_convertvector(t2, bf16x8);
    }
    // layer-2 weights for lane's 16 C/D rows (pairs for pk_fma)
    f32x2 w2p[8];
    #pragma unroll
    for (int m = 0; m < 8; ++m) {
        const int r0 = 8 * (m >> 1) + 4 * h + 2 * (m & 1);
        w2p[m][0] = W2[r0];
        w2p[m][1] = W2[r0 + 1];
    }

    const int tbase = blockIdx.x * ((BLOCK / 64) * TILES) + wave * TILES;
    const float* xb = x + (size_t)tbase * 192 + col * 3;   // my col's base
    float* ob = out + (size_t)tbase * 64 + lane;

    #pragma unroll
    for (int t = 0; t < TILES; ++t) {
        float S[2];
        #pragma unroll
        for (int gr = 0; gr < 2; ++gr) {
            // my point for this group: 64t + 32gr + col (imm offsets)
            const float x0 = xb[t * 192 + gr * 96 + 0];
            const float x1 = xb[t * 192 + gr * 96 + 1];
            const float x2 = xb[t * 192 + gr * 96 + 2];

            // 6 packed {sin,cos} pairs via trans pipe (bands h and 2+h)
            u32x4 u1, u2;
            u1[0] = pk_sc(x0 * FgA);
            u1[1] = pk_sc(x1 * FgA);
            u1[2] = pk_sc(x2 * FgA);
            f32x2 ex;
            ex[0] = h ? x2 : x0;
            ex[1] = h ? 1.0f : x1;     // bias multiplier lives in h=1
            u1[3] = __builtin_bit_cast(u32, __builtin_convertvector(ex, bf16x2));
            u2[0] = pk_sc(x0 * FgB);
            u2[1] = pk_sc(x1 * FgB);
            u2[2] = pk_sc(x2 * FgB);
            u2[3] = 0u;
            const bf16x8 B1 = __builtin_bit_cast(bf16x8, u1);
            const bf16x8 B2 = __builtin_bit_cast(bf16x8, u2);

            // layer 1: 2 chained 32x32x16 MFMAs -> 32 hidden x 32 points
            f32x16 acc = __builtin_amdgcn_mfma_f32_32x32x16_bf16(af1, B1, Z, 0, 0, 0);
            acc = __builtin_amdgcn_mfma_f32_32x32x16_bf16(af2, B2, acc, 0, 0, 0);

            // layer 2: relu + pk_fma over lane's 16 rows, fold halves
            f32x2 ps = {0.0f, 0.0f};
            #pragma unroll
            for (int m = 0; m < 8; ++m) {
                f32x2 v = {acc[2 * m], acc[2 * m + 1]};
                f32x2 zz = {0.f, 0.f};
                v = __builtin_elementwise_max(v, zz);
                ps = ps + v * w2p[m];
            }
            float s = ps[0] + ps[1];
            s += __shfl_xor(s, 32, 64);   // combine k-halves
            S[gr] = s;
        }
        // lane (h,col) stores point 32h+col of the tile
        const float v = h ? S[1] : S[0];
        ob[t * 64] = fmaxf(v + bias2, 0.0f);
    }
}

extern "C" void kernel_launch(void* const* d_in, const int* in_sizes, int n_in,
                              void* d_out, int out_size, void* d_ws, size_t ws_size,
                              hipStream_t stream) {
    const float* x  = (const float*)d_in[0];
    const float* W1 = (const float*)d_in[1];
    const float* b1 = (const float*)d_in[2];
    const float* W2 = (const float*)d_in[3];
    const float* b2 = (const float*)d_in[4];
    float* out = (float*)d_out;

    nerf_nolds<<<NBLK, BLOCK, 0, stream>>>(x, W1, b1, W2, b2, out);
}